// Round 6
// baseline (133.154 us; speedup 1.0000x reference)
//
#include <hip/hip_runtime.h>
#include <hip/hip_bf16.h>
#include <math.h>

#define NN     3072
#define NF     128
#define NHID   64
#define HEADS  8
#define LEN    8
#define NPATH  2048
#define NTK    4
#define NELEM  (NPATH*LEN)     // 16384
#define MAXDEG 128
#define SH     16              // 2 sets * 8 heads
#define KSPLIT 12
#define KCH    (NN / KSPLIT)   // 256
#define NADV   192             // k_nlogp blocks
#define NDIF   256             // k_diff_red blocks

// ---------------- init: zero histograms ----------------
__global__ void k_init(int* __restrict__ hist, int* __restrict__ histT) {
    int i = blockIdx.x * blockDim.x + threadIdx.x;
    if (i < NN) hist[i] = 0;
    if (i < NN * NTK) histT[i] = 0;
}

// ---------------- CSR build: one wave per row, 4 rows/block, float4 scan ----------------
__global__ void k_csr(const float* __restrict__ adj, int* __restrict__ cols,
                      int* __restrict__ cnt) {
    int row  = blockIdx.x * 4 + (threadIdx.x >> 6);
    int lane = threadIdx.x & 63;
    const float* ar = adj + (size_t)row * NN;
    int* cr = cols + (size_t)row * MAXDEG;
    int base = 0;
    for (int c0 = 0; c0 < NN; c0 += 256) {
        float4 v = *(const float4*)&ar[c0 + lane * 4];
        float e[4] = {v.x, v.y, v.z, v.w};
        #pragma unroll
        for (int q = 0; q < 4; ++q) {
            bool pred = e[q] > 0.f;
            unsigned long long b = __ballot(pred);
            int before = __popcll(b & ((1ull << lane) - 1ull));
            if (pred && (base + before) < MAXDEG) cr[base + before] = c0 + lane * 4 + q;
            base += __popcll(b);
        }
    }
    if (lane == 0) cnt[row] = base < MAXDEG ? base : MAXDEG;
}

// ---------------- Wh = features @ W (+ fused f1/f2 epilogue) ----------------
// Output layouts: wh[node][sh][hid], f1/f2[node][sh]
__global__ void k_gemm_wh(const float* __restrict__ feat,
                          const float* __restrict__ Wp, const float* __restrict__ Ws,
                          const float* __restrict__ ap, const float* __restrict__ as_,
                          float* __restrict__ wh, float* __restrict__ f1,
                          float* __restrict__ f2) {
    __shared__ float Fs[32][68];   // [k][r]
    __shared__ float Wsh[32][64];  // [k][c]
    int rt = blockIdx.x;
    int sh = blockIdx.y;
    int set = sh >> 3, head = sh & 7;
    const float* W = (set ? Ws : Wp) + (size_t)head * NF * NHID;  // [128][64]
    const float* a = (set ? as_ : ap) + (size_t)head * 2 * NHID;
    int tid = threadIdx.x;
    int tc = (tid & 15) * 4;
    int tr = (tid >> 4) * 4;
    float acc[4][4] = {};
    for (int k0 = 0; k0 < NF; k0 += 32) {
        for (int i = tid; i < 512; i += 256) {
            int r = i >> 3, kq = (i & 7) * 4;
            float4 v = *(const float4*)&feat[(size_t)(rt * 64 + r) * NF + k0 + kq];
            Fs[kq + 0][r] = v.x; Fs[kq + 1][r] = v.y;
            Fs[kq + 2][r] = v.z; Fs[kq + 3][r] = v.w;
        }
        for (int i = tid; i < 512; i += 256) {
            int k = i >> 4, cq = (i & 15) * 4;
            *(float4*)&Wsh[k][cq] = *(const float4*)&W[(size_t)(k0 + k) * NHID + cq];
        }
        __syncthreads();
        #pragma unroll
        for (int k = 0; k < 32; ++k) {
            float4 av = *(const float4*)&Fs[k][tr];
            float4 bv = *(const float4*)&Wsh[k][tc];
            float a_[4] = {av.x, av.y, av.z, av.w};
            float b_[4] = {bv.x, bv.y, bv.z, bv.w};
            #pragma unroll
            for (int i = 0; i < 4; ++i)
                #pragma unroll
                for (int j = 0; j < 4; ++j) acc[i][j] += a_[i] * b_[j];
        }
        __syncthreads();
    }
    for (int i = 0; i < 4; ++i)
        *(float4*)&wh[((size_t)(rt * 64 + tr + i) * SH + sh) * NHID + tc] =
            *(float4*)&acc[i][0];
    float4 a1 = *(const float4*)&a[tc];
    float4 a2 = *(const float4*)&a[NHID + tc];
    float p1[4], p2[4];
    #pragma unroll
    for (int i = 0; i < 4; ++i) {
        p1[i] = acc[i][0] * a1.x + acc[i][1] * a1.y + acc[i][2] * a1.z + acc[i][3] * a1.w;
        p2[i] = acc[i][0] * a2.x + acc[i][1] * a2.y + acc[i][2] * a2.z + acc[i][3] * a2.w;
    }
    #pragma unroll
    for (int o = 1; o < 16; o <<= 1) {
        #pragma unroll
        for (int i = 0; i < 4; ++i) {
            p1[i] += __shfl_xor(p1[i], o);
            p2[i] += __shfl_xor(p2[i], o);
        }
    }
    if ((tid & 15) == 0) {
        #pragma unroll
        for (int i = 0; i < 4; ++i) {
            f1[(size_t)(rt * 64 + tr + i) * SH + sh] = p1[i];
            f2[(size_t)(rt * 64 + tr + i) * SH + sh] = p2[i];
        }
    }
}

// ---------------- sparse GAT: 1 wave per node, ALL 16 sh fused ----------------
// wh[node][sh][hid], f1n/f2n[node][sh]; output xo unchanged layout
__global__ void k_gat(const float* __restrict__ wh, const float* __restrict__ f1n,
                      const float* __restrict__ f2n, const int* __restrict__ cols,
                      const int* __restrict__ cnt, float* __restrict__ xo) {
    __shared__ float attT[4][MAXDEG][16];   // 32 KB: [wave][neighbor][sh]
    __shared__ int   cls[4][MAXDEG];        // 2 KB
    int w = threadIdx.x >> 6;
    int lane = threadIdx.x & 63;
    int node = blockIdx.x * 4 + w;
    int deg = cnt[node];
    const int* cl = cols + (size_t)node * MAXDEG;

    // own-node f1 (wave-uniform)
    float f1v[16];
    {
        float4 t0 = *(const float4*)&f1n[node * SH + 0];
        float4 t1 = *(const float4*)&f1n[node * SH + 4];
        float4 t2 = *(const float4*)&f1n[node * SH + 8];
        float4 t3 = *(const float4*)&f1n[node * SH + 12];
        f1v[0]=t0.x; f1v[1]=t0.y; f1v[2]=t0.z; f1v[3]=t0.w;
        f1v[4]=t1.x; f1v[5]=t1.y; f1v[6]=t1.z; f1v[7]=t1.w;
        f1v[8]=t2.x; f1v[9]=t2.y; f1v[10]=t2.z; f1v[11]=t2.w;
        f1v[12]=t3.x; f1v[13]=t3.y; f1v[14]=t3.z; f1v[15]=t3.w;
    }

    // phase 1: e for slots lane and lane+64, all 16 sh
    float e0[16], e1[16];
    #pragma unroll
    for (int t = 0; t < 2; ++t) {
        int l = lane + t * 64;
        bool valid = l < deg;
        int j = valid ? cl[l] : 0;
        if (valid) cls[w][l] = j;
        const float* fp = &f2n[j * SH];
        float4 q0 = *(const float4*)&fp[0];
        float4 q1 = *(const float4*)&fp[4];
        float4 q2 = *(const float4*)&fp[8];
        float4 q3 = *(const float4*)&fp[12];
        float f2v[16] = {q0.x,q0.y,q0.z,q0.w, q1.x,q1.y,q1.z,q1.w,
                         q2.x,q2.y,q2.z,q2.w, q3.x,q3.y,q3.z,q3.w};
        float* e = t ? e1 : e0;
        #pragma unroll
        for (int s = 0; s < 16; ++s) {
            float x = f1v[s] + f2v[s];
            x = (x >= 0.f) ? x : 0.2f * x;
            e[s] = valid ? x : -1e30f;
        }
    }
    float m[16], inv[16];
    #pragma unroll
    for (int s = 0; s < 16; ++s) m[s] = fmaxf(e0[s], e1[s]);
    #pragma unroll
    for (int o = 32; o; o >>= 1)
        #pragma unroll
        for (int s = 0; s < 16; ++s) m[s] = fmaxf(m[s], __shfl_xor(m[s], o));
    float ex0[16], ex1[16], sl[16];
    #pragma unroll
    for (int s = 0; s < 16; ++s) {
        ex0[s] = expf(e0[s] - m[s]);       // invalid slots underflow to 0
        ex1[s] = expf(e1[s] - m[s]);
        sl[s] = ex0[s] + ex1[s];
    }
    #pragma unroll
    for (int o = 32; o; o >>= 1)
        #pragma unroll
        for (int s = 0; s < 16; ++s) sl[s] += __shfl_xor(sl[s], o);
    #pragma unroll
    for (int s = 0; s < 16; ++s) inv[s] = 1.f / sl[s];
    // store attT rows (64B per slot, contiguous per lane)
    *(float4*)&attT[w][lane][0]  = make_float4(ex0[0], ex0[1], ex0[2], ex0[3]);
    *(float4*)&attT[w][lane][4]  = make_float4(ex0[4], ex0[5], ex0[6], ex0[7]);
    *(float4*)&attT[w][lane][8]  = make_float4(ex0[8], ex0[9], ex0[10], ex0[11]);
    *(float4*)&attT[w][lane][12] = make_float4(ex0[12], ex0[13], ex0[14], ex0[15]);
    *(float4*)&attT[w][lane+64][0]  = make_float4(ex1[0], ex1[1], ex1[2], ex1[3]);
    *(float4*)&attT[w][lane+64][4]  = make_float4(ex1[4], ex1[5], ex1[6], ex1[7]);
    *(float4*)&attT[w][lane+64][8]  = make_float4(ex1[8], ex1[9], ex1[10], ex1[11]);
    *(float4*)&attT[w][lane+64][12] = make_float4(ex1[12], ex1[13], ex1[14], ex1[15]);

    // phase 2: gather — per neighbor: 1 base addr + 16 imm-offset loads + 4 b128 broadcasts
    float acc[16] = {};
    for (int l = 0; l < deg; ++l) {
        int j = cls[w][l];
        const float* wr = wh + (size_t)j * (SH * NHID) + lane;
        float4 a0 = *(const float4*)&attT[w][l][0];
        float4 a1 = *(const float4*)&attT[w][l][4];
        float4 a2 = *(const float4*)&attT[w][l][8];
        float4 a3 = *(const float4*)&attT[w][l][12];
        acc[0]  += a0.x * wr[0 * 64];
        acc[1]  += a0.y * wr[1 * 64];
        acc[2]  += a0.z * wr[2 * 64];
        acc[3]  += a0.w * wr[3 * 64];
        acc[4]  += a1.x * wr[4 * 64];
        acc[5]  += a1.y * wr[5 * 64];
        acc[6]  += a1.z * wr[6 * 64];
        acc[7]  += a1.w * wr[7 * 64];
        acc[8]  += a2.x * wr[8 * 64];
        acc[9]  += a2.y * wr[9 * 64];
        acc[10] += a2.z * wr[10 * 64];
        acc[11] += a2.w * wr[11 * 64];
        acc[12] += a3.x * wr[12 * 64];
        acc[13] += a3.y * wr[13 * 64];
        acc[14] += a3.z * wr[14 * 64];
        acc[15] += a3.w * wr[15 * 64];
    }
    #pragma unroll
    for (int s = 0; s < 16; ++s) {
        float v = acc[s] * inv[s];
        v = (v > 0.f) ? v : (expf(v) - 1.f);   // ELU
        int set = s >> 3, head = s & 7;
        xo[((size_t)set * NN + node) * (HEADS * NHID) + head * NHID + lane] = v;
    }
}

// ---------------- node + (node,task) histograms ----------------
__global__ void k_hist(const int* __restrict__ path, const int* __restrict__ task,
                       int* __restrict__ hist, int* __restrict__ histT) {
    int i = blockIdx.x * blockDim.x + threadIdx.x;
    if (i < NELEM) {
        int node = path[i];
        atomicAdd(&hist[node], 1);
        atomicAdd(&histT[node * NTK + task[i]], 1);
    }
}

// ---------------- per-node logp + adv partials (no same-address atomics) ----------------
__global__ void k_nlogp(const float* __restrict__ S, const float* __restrict__ Wsc,
                        const float* __restrict__ bsc, const int* __restrict__ histT,
                        float* __restrict__ padv) {
    __shared__ float red[4];
    int wave = threadIdx.x >> 6;
    int lane = threadIdx.x & 63;
    float sloc = 0.f;
    #pragma unroll
    for (int i = 0; i < 4; ++i) {
        int w = blockIdx.x * 16 + wave * 4 + i;
        const float* row = S + (size_t)w * (HEADS * NHID);
        float4 v0 = *(const float4*)&row[lane * 8];
        float4 v1 = *(const float4*)&row[lane * 8 + 4];
        float vv[8] = {v0.x, v0.y, v0.z, v0.w, v1.x, v1.y, v1.z, v1.w};
        float p[4] = {0.f, 0.f, 0.f, 0.f};
        #pragma unroll
        for (int qq = 0; qq < 8; ++qq) {
            float4 wv = *(const float4*)&Wsc[(lane * 8 + qq) * 4];
            p[0] += vv[qq] * wv.x; p[1] += vv[qq] * wv.y;
            p[2] += vv[qq] * wv.z; p[3] += vv[qq] * wv.w;
        }
        for (int o = 32; o; o >>= 1) {
            p[0] += __shfl_xor(p[0], o); p[1] += __shfl_xor(p[1], o);
            p[2] += __shfl_xor(p[2], o); p[3] += __shfl_xor(p[3], o);
        }
        if (lane == 0) {
            float sg[4], mx = -1e30f;
            for (int j = 0; j < 4; ++j) {
                sg[j] = 1.f / (1.f + expf(-(p[j] + bsc[j])));
                mx = fmaxf(mx, sg[j]);
            }
            float ex[4], se = 0.f;
            for (int j = 0; j < 4; ++j) { ex[j] = expf(sg[j] - mx); se += ex[j]; }
            float pr[4], pe = 0.f;
            for (int j = 0; j < 4; ++j) { pr[j] = ex[j] / se; }
            for (int j = 0; j < 4; ++j) { pe += expf(pr[j]); }
            float lse = logf(pe);
            for (int j = 0; j < 4; ++j)
                sloc += (float)histT[w * NTK + j] * (pr[j] - lse);
        }
    }
    if (lane == 0) red[wave] = sloc;
    __syncthreads();
    if (threadIdx.x == 0)
        padv[blockIdx.x] = red[0] + red[1] + red[2] + red[3];
}

// ---------------- diff partial: Dp[z] = S^T diag(c) P over one K-chunk ----------------
__global__ void k_diff_part(const float* __restrict__ S, const float* __restrict__ P,
                            const int* __restrict__ hist, float* __restrict__ Dp) {
    __shared__ float As[64][68];
    __shared__ float Bs[64][68];
    int a0 = blockIdx.y * 64, b0 = blockIdx.x * 64;
    int kbase = blockIdx.z * KCH;
    int tr = (threadIdx.x >> 4) * 4, tc = (threadIdx.x & 15) * 4;
    float acc[4][4] = {};
    for (int k0 = 0; k0 < KCH; k0 += 64) {
        for (int i = threadIdx.x; i < 64 * 16; i += 256) {
            int k = i >> 4, c4 = (i & 15) * 4;
            int krow = kbase + k0 + k;
            float wgt = (float)hist[krow];
            float4 sv = *(const float4*)&S[(size_t)krow * 512 + a0 + c4];
            As[k][c4 + 0] = sv.x * wgt; As[k][c4 + 1] = sv.y * wgt;
            As[k][c4 + 2] = sv.z * wgt; As[k][c4 + 3] = sv.w * wgt;
            float4 pv = *(const float4*)&P[(size_t)krow * 512 + b0 + c4];
            Bs[k][c4 + 0] = pv.x; Bs[k][c4 + 1] = pv.y;
            Bs[k][c4 + 2] = pv.z; Bs[k][c4 + 3] = pv.w;
        }
        __syncthreads();
        #pragma unroll
        for (int k = 0; k < 64; ++k) {
            float4 av = *(const float4*)&As[k][tr];
            float4 bv = *(const float4*)&Bs[k][tc];
            float a_[4] = {av.x, av.y, av.z, av.w};
            float b_[4] = {bv.x, bv.y, bv.z, bv.w};
            #pragma unroll
            for (int i = 0; i < 4; ++i)
                #pragma unroll
                for (int j = 0; j < 4; ++j) acc[i][j] += a_[i] * b_[j];
        }
        __syncthreads();
    }
    float* dst = Dp + (size_t)blockIdx.z * 512 * 512;
    #pragma unroll
    for (int i = 0; i < 4; ++i)
        *(float4*)&dst[(size_t)(a0 + tr + i) * 512 + b0 + tc] = *(float4*)&acc[i][0];
}

// ---------------- diff reduce: pdiff[b] = partial sum((sum_z Dp[z])^2) ----------------
__global__ void k_diff_red(const float* __restrict__ Dp, float* __restrict__ pdiff) {
    __shared__ float red[256];
    int e4 = blockIdx.x * 256 + threadIdx.x;   // float4 index, 65536 total
    float4 a = {0.f, 0.f, 0.f, 0.f};
    for (int z = 0; z < KSPLIT; ++z) {
        float4 v = *(const float4*)&Dp[(size_t)z * 512 * 512 + (size_t)e4 * 4];
        a.x += v.x; a.y += v.y; a.z += v.z; a.w += v.w;
    }
    red[threadIdx.x] = a.x * a.x + a.y * a.y + a.z * a.z + a.w * a.w;
    __syncthreads();
    for (int o = 128; o; o >>= 1) {
        if (threadIdx.x < o) red[threadIdx.x] += red[threadIdx.x + o];
        __syncthreads();
    }
    if (threadIdx.x == 0) pdiff[blockIdx.x] = red[0];
}

// ---------------- final scalar outputs (single block; no atomics anywhere) ----------------
__global__ void k_scalars(const float* __restrict__ padv, const float* __restrict__ pdiff,
                          float* __restrict__ out) {
    __shared__ float red[256];
    int t = threadIdx.x;
    red[t] = (t < NADV) ? padv[t] : 0.f;
    __syncthreads();
    for (int o = 128; o; o >>= 1) {
        if (t < o) red[t] += red[t + o];
        __syncthreads();
    }
    if (t == 0) out[NPATH] = -red[0] * (1.f / (float)NELEM);
    __syncthreads();
    red[t] = pdiff[t];
    __syncthreads();
    for (int o = 128; o; o >>= 1) {
        if (t < o) red[t] += red[t + o];
        __syncthreads();
    }
    if (t == 0) out[NPATH + 1] = red[0];
}

// ---------------- final classifier x = sigmoid([S|P]_path @ Wc + bc) ----------------
__global__ void k_final(const float* __restrict__ S, const float* __restrict__ P,
                        const int* __restrict__ path, const float* __restrict__ Wc,
                        const float* __restrict__ bc, float* __restrict__ out) {
    __shared__ float red[256];
    int p = blockIdx.x;
    float s = 0.f;
    for (int m4 = threadIdx.x; m4 < 2048; m4 += 256) {
        int m = m4 * 4;
        int l = m >> 10, w = m & 1023;
        int node = path[p * LEN + l];
        float4 wv = *(const float4*)&Wc[m];
        const float* src = (w < 512) ? &S[(size_t)node * 512 + w]
                                     : &P[(size_t)node * 512 + (w - 512)];
        float4 xv = *(const float4*)src;
        s += xv.x * wv.x + xv.y * wv.y + xv.z * wv.z + xv.w * wv.w;
    }
    red[threadIdx.x] = s;
    __syncthreads();
    for (int o = 128; o; o >>= 1) {
        if (threadIdx.x < o) red[threadIdx.x] += red[threadIdx.x + o];
        __syncthreads();
    }
    if (threadIdx.x == 0) out[p] = 1.f / (1.f + expf(-(red[0] + bc[0])));
}

extern "C" void kernel_launch(void* const* d_in, const int* in_sizes, int n_in,
                              void* d_out, int out_size, void* d_ws, size_t ws_size,
                              hipStream_t stream) {
    const float* feat = (const float*)d_in[0];
    const float* adj  = (const float*)d_in[1];
    const int*   path = (const int*)d_in[2];
    const int*   task = (const int*)d_in[3];
    const float* Wp   = (const float*)d_in[4];
    const float* ap   = (const float*)d_in[5];
    const float* Ws   = (const float*)d_in[6];
    const float* as_  = (const float*)d_in[7];
    const float* Wsc  = (const float*)d_in[8];
    const float* bsc  = (const float*)d_in[9];
    const float* Wc   = (const float*)d_in[10];
    const float* bc   = (const float*)d_in[11];
    float* out = (float*)d_out;

    // workspace layout
    float* wh    = (float*)d_ws;                   // NN*SH*NHID (new layout [node][sh][hid])
    float* f1    = wh + (size_t)NN * SH * NHID;    // NN*SH ([node][sh])
    float* f2    = f1 + (size_t)NN * SH;
    float* xo    = f2 + (size_t)NN * SH;           // 2*3072*512
    float* Dp    = xo + (size_t)2 * NN * 512;      // KSPLIT*512*512
    float* padv  = Dp + (size_t)KSPLIT * 512 * 512;
    float* pdiff = padv + NADV;
    int*   cols  = (int*)(pdiff + NDIF);
    int*   cnt   = cols + (size_t)NN * MAXDEG;
    int*   hist  = cnt + NN;
    int*   histT = hist + NN;

    float* Pm = xo;                        // private (set 0)
    float* Sm = xo + (size_t)NN * 512;     // share   (set 1)

    k_init<<<(NN * NTK + 255) / 256, 256, 0, stream>>>(hist, histT);
    k_hist<<<(NELEM + 255) / 256, 256, 0, stream>>>(path, task, hist, histT);
    k_csr<<<NN / 4, 256, 0, stream>>>(adj, cols, cnt);
    k_gemm_wh<<<dim3(NN / 64, SH), 256, 0, stream>>>(feat, Wp, Ws, ap, as_, wh, f1, f2);
    k_gat<<<NN / 4, 256, 0, stream>>>(wh, f1, f2, cols, cnt, xo);
    k_nlogp<<<NADV, 256, 0, stream>>>(Sm, Wsc, bsc, histT, padv);
    k_diff_part<<<dim3(8, 8, KSPLIT), 256, 0, stream>>>(Sm, Pm, hist, Dp);
    k_diff_red<<<NDIF, 256, 0, stream>>>(Dp, pdiff);
    k_scalars<<<1, 256, 0, stream>>>(padv, pdiff, out);
    k_final<<<NPATH, 256, 0, stream>>>(Sm, Pm, path, Wc, bc, out);
}

// Round 7
// 114.028 us; speedup vs baseline: 1.1677x; 1.1677x over previous
//
#include <hip/hip_runtime.h>
#include <hip/hip_bf16.h>
#include <math.h>

#define NN     3072
#define NF     128
#define NHID   64
#define HEADS  8
#define LEN    8
#define NPATH  2048
#define NTK    4
#define NELEM  (NPATH*LEN)     // 16384
#define MAXDEG 128
#define SH     16              // 2 sets * 8 heads
#define KSPLIT 12
#define KCH    (NN / KSPLIT)   // 256
#define NADV   192             // k_nlogp blocks
#define NDIF   256             // k_diff_red blocks

// ---------------- init: zero histograms ----------------
__global__ void k_init(int* __restrict__ hist, int* __restrict__ histT) {
    int i = blockIdx.x * blockDim.x + threadIdx.x;
    if (i < NN) hist[i] = 0;
    if (i < NN * NTK) histT[i] = 0;
}

// ---------------- CSR build: one wave per row, 4 rows/block, float4 scan ----------------
__global__ void k_csr(const float* __restrict__ adj, int* __restrict__ cols,
                      int* __restrict__ cnt) {
    int row  = blockIdx.x * 4 + (threadIdx.x >> 6);
    int lane = threadIdx.x & 63;
    const float* ar = adj + (size_t)row * NN;
    int* cr = cols + (size_t)row * MAXDEG;
    int base = 0;
    for (int c0 = 0; c0 < NN; c0 += 256) {
        float4 v = *(const float4*)&ar[c0 + lane * 4];
        float e[4] = {v.x, v.y, v.z, v.w};
        #pragma unroll
        for (int q = 0; q < 4; ++q) {
            bool pred = e[q] > 0.f;
            unsigned long long b = __ballot(pred);
            int before = __popcll(b & ((1ull << lane) - 1ull));
            if (pred && (base + before) < MAXDEG) cr[base + before] = c0 + lane * 4 + q;
            base += __popcll(b);
        }
    }
    if (lane == 0) cnt[row] = base < MAXDEG ? base : MAXDEG;
}

// ---------------- Wh = features @ W (+ fused f1/f2 epilogue) ----------------
// Output layouts: whg[g][node][sg][hid] (g=sh>>2, sg=sh&3), f1g/f2g[g][node][sg]
__global__ void k_gemm_wh(const float* __restrict__ feat,
                          const float* __restrict__ Wp, const float* __restrict__ Ws,
                          const float* __restrict__ ap, const float* __restrict__ as_,
                          float* __restrict__ whg, float* __restrict__ f1g,
                          float* __restrict__ f2g) {
    __shared__ float Fs[32][68];   // [k][r]
    __shared__ float Wsh[32][64];  // [k][c]
    int rt = blockIdx.x;
    int sh = blockIdx.y;
    int set = sh >> 3, head = sh & 7;
    int g = sh >> 2, sg = sh & 3;
    const float* W = (set ? Ws : Wp) + (size_t)head * NF * NHID;  // [128][64]
    const float* a = (set ? as_ : ap) + (size_t)head * 2 * NHID;
    int tid = threadIdx.x;
    int tc = (tid & 15) * 4;
    int tr = (tid >> 4) * 4;
    float acc[4][4] = {};
    for (int k0 = 0; k0 < NF; k0 += 32) {
        for (int i = tid; i < 512; i += 256) {
            int r = i >> 3, kq = (i & 7) * 4;
            float4 v = *(const float4*)&feat[(size_t)(rt * 64 + r) * NF + k0 + kq];
            Fs[kq + 0][r] = v.x; Fs[kq + 1][r] = v.y;
            Fs[kq + 2][r] = v.z; Fs[kq + 3][r] = v.w;
        }
        for (int i = tid; i < 512; i += 256) {
            int k = i >> 4, cq = (i & 15) * 4;
            *(float4*)&Wsh[k][cq] = *(const float4*)&W[(size_t)(k0 + k) * NHID + cq];
        }
        __syncthreads();
        #pragma unroll
        for (int k = 0; k < 32; ++k) {
            float4 av = *(const float4*)&Fs[k][tr];
            float4 bv = *(const float4*)&Wsh[k][tc];
            float a_[4] = {av.x, av.y, av.z, av.w};
            float b_[4] = {bv.x, bv.y, bv.z, bv.w};
            #pragma unroll
            for (int i = 0; i < 4; ++i)
                #pragma unroll
                for (int j = 0; j < 4; ++j) acc[i][j] += a_[i] * b_[j];
        }
        __syncthreads();
    }
    #pragma unroll
    for (int i = 0; i < 4; ++i)
        *(float4*)&whg[(((size_t)g * NN + rt * 64 + tr + i) * 4 + sg) * NHID + tc] =
            *(float4*)&acc[i][0];
    float4 a1 = *(const float4*)&a[tc];
    float4 a2 = *(const float4*)&a[NHID + tc];
    float p1[4], p2[4];
    #pragma unroll
    for (int i = 0; i < 4; ++i) {
        p1[i] = acc[i][0] * a1.x + acc[i][1] * a1.y + acc[i][2] * a1.z + acc[i][3] * a1.w;
        p2[i] = acc[i][0] * a2.x + acc[i][1] * a2.y + acc[i][2] * a2.z + acc[i][3] * a2.w;
    }
    #pragma unroll
    for (int o = 1; o < 16; o <<= 1) {
        #pragma unroll
        for (int i = 0; i < 4; ++i) {
            p1[i] += __shfl_xor(p1[i], o);
            p2[i] += __shfl_xor(p2[i], o);
        }
    }
    if ((tid & 15) == 0) {
        #pragma unroll
        for (int i = 0; i < 4; ++i) {
            f1g[((size_t)g * NN + rt * 64 + tr + i) * 4 + sg] = p1[i];
            f2g[((size_t)g * NN + rt * 64 + tr + i) * 4 + sg] = p2[i];
        }
    }
}

// ---------------- sparse GAT: 1 wave per (node, sh-group of 4), XCD-partitioned ----------------
// whg[g][node][4][64], f1g/f2g[g][node][4]; per-XCD working set ~3.4 MB (fits 4 MB L2)
__global__ void k_gat(const float* __restrict__ whg, const float* __restrict__ f1g,
                      const float* __restrict__ f2g, const int* __restrict__ cols,
                      const int* __restrict__ cnt, float* __restrict__ xo) {
    __shared__ float attT[4][MAXDEG][4];   // 8 KB
    __shared__ int   cls[4][MAXDEG];       // 2 KB
    int b = blockIdx.x;                    // 0..3071
    int g = (b & 7) >> 1;                  // sh-group -> XCD pair {2g,2g+1}
    int node4 = ((b >> 3) << 1) | (b & 1); // 0..767
    int w = threadIdx.x >> 6;
    int lane = threadIdx.x & 63;
    int node = node4 * 4 + w;
    int deg = cnt[node];
    const int* cl = cols + (size_t)node * MAXDEG;
    const float* f2p = f2g + (size_t)g * NN * 4;
    float4 f1q = *(const float4*)&f1g[((size_t)g * NN + node) * 4];
    float f1v[4] = {f1q.x, f1q.y, f1q.z, f1q.w};

    // phase 1: attention logits for slots lane, lane+64 across 4 sh
    float e0[4], e1[4];
    #pragma unroll
    for (int t = 0; t < 2; ++t) {
        int l = lane + t * 64;
        bool valid = l < deg;
        int j = valid ? cl[l] : 0;
        if (valid) cls[w][l] = j;
        float4 q = *(const float4*)&f2p[(size_t)j * 4];
        float f2v[4] = {q.x, q.y, q.z, q.w};
        float* e = t ? e1 : e0;
        #pragma unroll
        for (int s = 0; s < 4; ++s) {
            float x = f1v[s] + f2v[s];
            x = (x >= 0.f) ? x : 0.2f * x;
            e[s] = valid ? x : -1e30f;
        }
    }
    float m[4], sl[4], inv[4];
    #pragma unroll
    for (int s = 0; s < 4; ++s) m[s] = fmaxf(e0[s], e1[s]);
    #pragma unroll
    for (int o = 32; o; o >>= 1)
        #pragma unroll
        for (int s = 0; s < 4; ++s) m[s] = fmaxf(m[s], __shfl_xor(m[s], o));
    float ex0[4], ex1[4];
    #pragma unroll
    for (int s = 0; s < 4; ++s) {
        ex0[s] = expf(e0[s] - m[s]);
        ex1[s] = expf(e1[s] - m[s]);
        sl[s] = ex0[s] + ex1[s];
    }
    #pragma unroll
    for (int o = 32; o; o >>= 1)
        #pragma unroll
        for (int s = 0; s < 4; ++s) sl[s] += __shfl_xor(sl[s], o);
    #pragma unroll
    for (int s = 0; s < 4; ++s) inv[s] = 1.f / sl[s];
    *(float4*)&attT[w][lane][0]      = make_float4(ex0[0], ex0[1], ex0[2], ex0[3]);
    *(float4*)&attT[w][lane + 64][0] = make_float4(ex1[0], ex1[1], ex1[2], ex1[3]);

    // phase 2: gather — per neighbor: 1 base + 4 imm-offset loads + 1 LDS b128 + 4 FMA
    const float* base = whg + (size_t)g * NN * 256;
    float acc0 = 0.f, acc1 = 0.f, acc2 = 0.f, acc3 = 0.f;
    int l = 0;
    for (; l + 2 <= deg; l += 2) {
        int ja = cls[w][l], jb = cls[w][l + 1];
        const float* wa = base + (size_t)ja * 256 + lane;
        const float* wb = base + (size_t)jb * 256 + lane;
        float4 aa = *(const float4*)&attT[w][l][0];
        float4 ab = *(const float4*)&attT[w][l + 1][0];
        float va0 = wa[0], va1 = wa[64], va2 = wa[128], va3 = wa[192];
        float vb0 = wb[0], vb1 = wb[64], vb2 = wb[128], vb3 = wb[192];
        acc0 += aa.x * va0; acc1 += aa.y * va1; acc2 += aa.z * va2; acc3 += aa.w * va3;
        acc0 += ab.x * vb0; acc1 += ab.y * vb1; acc2 += ab.z * vb2; acc3 += ab.w * vb3;
    }
    if (l < deg) {
        int j = cls[w][l];
        const float* wr = base + (size_t)j * 256 + lane;
        float4 a4 = *(const float4*)&attT[w][l][0];
        acc0 += a4.x * wr[0];  acc1 += a4.y * wr[64];
        acc2 += a4.z * wr[128]; acc3 += a4.w * wr[192];
    }
    float accv[4] = {acc0, acc1, acc2, acc3};
    #pragma unroll
    for (int s = 0; s < 4; ++s) {
        float v = accv[s] * inv[s];
        v = (v > 0.f) ? v : (expf(v) - 1.f);   // ELU
        int sh = g * 4 + s;
        int set = sh >> 3, head = sh & 7;
        xo[((size_t)set * NN + node) * (HEADS * NHID) + head * NHID + lane] = v;
    }
}

// ---------------- node + (node,task) histograms ----------------
__global__ void k_hist(const int* __restrict__ path, const int* __restrict__ task,
                       int* __restrict__ hist, int* __restrict__ histT) {
    int i = blockIdx.x * blockDim.x + threadIdx.x;
    if (i < NELEM) {
        int node = path[i];
        atomicAdd(&hist[node], 1);
        atomicAdd(&histT[node * NTK + task[i]], 1);
    }
}

// ---------------- per-node logp + adv partials (no same-address atomics) ----------------
__global__ void k_nlogp(const float* __restrict__ S, const float* __restrict__ Wsc,
                        const float* __restrict__ bsc, const int* __restrict__ histT,
                        float* __restrict__ padv) {
    __shared__ float red[4];
    int wave = threadIdx.x >> 6;
    int lane = threadIdx.x & 63;
    float sloc = 0.f;
    #pragma unroll
    for (int i = 0; i < 4; ++i) {
        int w = blockIdx.x * 16 + wave * 4 + i;
        const float* row = S + (size_t)w * (HEADS * NHID);
        float4 v0 = *(const float4*)&row[lane * 8];
        float4 v1 = *(const float4*)&row[lane * 8 + 4];
        float vv[8] = {v0.x, v0.y, v0.z, v0.w, v1.x, v1.y, v1.z, v1.w};
        float p[4] = {0.f, 0.f, 0.f, 0.f};
        #pragma unroll
        for (int qq = 0; qq < 8; ++qq) {
            float4 wv = *(const float4*)&Wsc[(lane * 8 + qq) * 4];
            p[0] += vv[qq] * wv.x; p[1] += vv[qq] * wv.y;
            p[2] += vv[qq] * wv.z; p[3] += vv[qq] * wv.w;
        }
        for (int o = 32; o; o >>= 1) {
            p[0] += __shfl_xor(p[0], o); p[1] += __shfl_xor(p[1], o);
            p[2] += __shfl_xor(p[2], o); p[3] += __shfl_xor(p[3], o);
        }
        if (lane == 0) {
            float sg[4], mx = -1e30f;
            for (int j = 0; j < 4; ++j) {
                sg[j] = 1.f / (1.f + expf(-(p[j] + bsc[j])));
                mx = fmaxf(mx, sg[j]);
            }
            float ex[4], se = 0.f;
            for (int j = 0; j < 4; ++j) { ex[j] = expf(sg[j] - mx); se += ex[j]; }
            float pr[4], pe = 0.f;
            for (int j = 0; j < 4; ++j) { pr[j] = ex[j] / se; }
            for (int j = 0; j < 4; ++j) { pe += expf(pr[j]); }
            float lse = logf(pe);
            for (int j = 0; j < 4; ++j)
                sloc += (float)histT[w * NTK + j] * (pr[j] - lse);
        }
    }
    if (lane == 0) red[wave] = sloc;
    __syncthreads();
    if (threadIdx.x == 0)
        padv[blockIdx.x] = red[0] + red[1] + red[2] + red[3];
}

// ---------------- diff partial: Dp[z] = S^T diag(c) P over one K-chunk ----------------
__global__ void k_diff_part(const float* __restrict__ S, const float* __restrict__ P,
                            const int* __restrict__ hist, float* __restrict__ Dp) {
    __shared__ float As[64][68];
    __shared__ float Bs[64][68];
    int a0 = blockIdx.y * 64, b0 = blockIdx.x * 64;
    int kbase = blockIdx.z * KCH;
    int tr = (threadIdx.x >> 4) * 4, tc = (threadIdx.x & 15) * 4;
    float acc[4][4] = {};
    for (int k0 = 0; k0 < KCH; k0 += 64) {
        for (int i = threadIdx.x; i < 64 * 16; i += 256) {
            int k = i >> 4, c4 = (i & 15) * 4;
            int krow = kbase + k0 + k;
            float wgt = (float)hist[krow];
            float4 sv = *(const float4*)&S[(size_t)krow * 512 + a0 + c4];
            As[k][c4 + 0] = sv.x * wgt; As[k][c4 + 1] = sv.y * wgt;
            As[k][c4 + 2] = sv.z * wgt; As[k][c4 + 3] = sv.w * wgt;
            float4 pv = *(const float4*)&P[(size_t)krow * 512 + b0 + c4];
            Bs[k][c4 + 0] = pv.x; Bs[k][c4 + 1] = pv.y;
            Bs[k][c4 + 2] = pv.z; Bs[k][c4 + 3] = pv.w;
        }
        __syncthreads();
        #pragma unroll
        for (int k = 0; k < 64; ++k) {
            float4 av = *(const float4*)&As[k][tr];
            float4 bv = *(const float4*)&Bs[k][tc];
            float a_[4] = {av.x, av.y, av.z, av.w};
            float b_[4] = {bv.x, bv.y, bv.z, bv.w};
            #pragma unroll
            for (int i = 0; i < 4; ++i)
                #pragma unroll
                for (int j = 0; j < 4; ++j) acc[i][j] += a_[i] * b_[j];
        }
        __syncthreads();
    }
    float* dst = Dp + (size_t)blockIdx.z * 512 * 512;
    #pragma unroll
    for (int i = 0; i < 4; ++i)
        *(float4*)&dst[(size_t)(a0 + tr + i) * 512 + b0 + tc] = *(float4*)&acc[i][0];
}

// ---------------- diff reduce: pdiff[b] = partial sum((sum_z Dp[z])^2) ----------------
__global__ void k_diff_red(const float* __restrict__ Dp, float* __restrict__ pdiff) {
    __shared__ float red[256];
    int e4 = blockIdx.x * 256 + threadIdx.x;   // float4 index, 65536 total
    float4 a = {0.f, 0.f, 0.f, 0.f};
    for (int z = 0; z < KSPLIT; ++z) {
        float4 v = *(const float4*)&Dp[(size_t)z * 512 * 512 + (size_t)e4 * 4];
        a.x += v.x; a.y += v.y; a.z += v.z; a.w += v.w;
    }
    red[threadIdx.x] = a.x * a.x + a.y * a.y + a.z * a.z + a.w * a.w;
    __syncthreads();
    for (int o = 128; o; o >>= 1) {
        if (threadIdx.x < o) red[threadIdx.x] += red[threadIdx.x + o];
        __syncthreads();
    }
    if (threadIdx.x == 0) pdiff[blockIdx.x] = red[0];
}

// ---------------- final scalar outputs (single block; no atomics anywhere) ----------------
__global__ void k_scalars(const float* __restrict__ padv, const float* __restrict__ pdiff,
                          float* __restrict__ out) {
    __shared__ float red[256];
    int t = threadIdx.x;
    red[t] = (t < NADV) ? padv[t] : 0.f;
    __syncthreads();
    for (int o = 128; o; o >>= 1) {
        if (t < o) red[t] += red[t + o];
        __syncthreads();
    }
    if (t == 0) out[NPATH] = -red[0] * (1.f / (float)NELEM);
    __syncthreads();
    red[t] = pdiff[t];
    __syncthreads();
    for (int o = 128; o; o >>= 1) {
        if (t < o) red[t] += red[t + o];
        __syncthreads();
    }
    if (t == 0) out[NPATH + 1] = red[0];
}

// ---------------- final classifier x = sigmoid([S|P]_path @ Wc + bc) ----------------
__global__ void k_final(const float* __restrict__ S, const float* __restrict__ P,
                        const int* __restrict__ path, const float* __restrict__ Wc,
                        const float* __restrict__ bc, float* __restrict__ out) {
    __shared__ float red[256];
    int p = blockIdx.x;
    float s = 0.f;
    for (int m4 = threadIdx.x; m4 < 2048; m4 += 256) {
        int m = m4 * 4;
        int l = m >> 10, w = m & 1023;
        int node = path[p * LEN + l];
        float4 wv = *(const float4*)&Wc[m];
        const float* src = (w < 512) ? &S[(size_t)node * 512 + w]
                                     : &P[(size_t)node * 512 + (w - 512)];
        float4 xv = *(const float4*)src;
        s += xv.x * wv.x + xv.y * wv.y + xv.z * wv.z + xv.w * wv.w;
    }
    red[threadIdx.x] = s;
    __syncthreads();
    for (int o = 128; o; o >>= 1) {
        if (threadIdx.x < o) red[threadIdx.x] += red[threadIdx.x + o];
        __syncthreads();
    }
    if (threadIdx.x == 0) out[p] = 1.f / (1.f + expf(-(red[0] + bc[0])));
}

extern "C" void kernel_launch(void* const* d_in, const int* in_sizes, int n_in,
                              void* d_out, int out_size, void* d_ws, size_t ws_size,
                              hipStream_t stream) {
    const float* feat = (const float*)d_in[0];
    const float* adj  = (const float*)d_in[1];
    const int*   path = (const int*)d_in[2];
    const int*   task = (const int*)d_in[3];
    const float* Wp   = (const float*)d_in[4];
    const float* ap   = (const float*)d_in[5];
    const float* Ws   = (const float*)d_in[6];
    const float* as_  = (const float*)d_in[7];
    const float* Wsc  = (const float*)d_in[8];
    const float* bsc  = (const float*)d_in[9];
    const float* Wc   = (const float*)d_in[10];
    const float* bc   = (const float*)d_in[11];
    float* out = (float*)d_out;

    // workspace layout
    float* whg   = (float*)d_ws;                   // NN*SH*NHID ([g][node][4][64])
    float* f1g   = whg + (size_t)NN * SH * NHID;   // NN*SH ([g][node][4])
    float* f2g   = f1g + (size_t)NN * SH;
    float* xo    = f2g + (size_t)NN * SH;          // 2*3072*512
    float* Dp    = xo + (size_t)2 * NN * 512;      // KSPLIT*512*512
    float* padv  = Dp + (size_t)KSPLIT * 512 * 512;
    float* pdiff = padv + NADV;
    int*   cols  = (int*)(pdiff + NDIF);
    int*   cnt   = cols + (size_t)NN * MAXDEG;
    int*   hist  = cnt + NN;
    int*   histT = hist + NN;

    float* Pm = xo;                        // private (set 0)
    float* Sm = xo + (size_t)NN * 512;     // share   (set 1)

    k_init<<<(NN * NTK + 255) / 256, 256, 0, stream>>>(hist, histT);
    k_hist<<<(NELEM + 255) / 256, 256, 0, stream>>>(path, task, hist, histT);
    k_csr<<<NN / 4, 256, 0, stream>>>(adj, cols, cnt);
    k_gemm_wh<<<dim3(NN / 64, SH), 256, 0, stream>>>(feat, Wp, Ws, ap, as_, whg, f1g, f2g);
    k_gat<<<NN, 256, 0, stream>>>(whg, f1g, f2g, cols, cnt, xo);
    k_nlogp<<<NADV, 256, 0, stream>>>(Sm, Wsc, bsc, histT, padv);
    k_diff_part<<<dim3(8, 8, KSPLIT), 256, 0, stream>>>(Sm, Pm, hist, Dp);
    k_diff_red<<<NDIF, 256, 0, stream>>>(Dp, pdiff);
    k_scalars<<<1, 256, 0, stream>>>(padv, pdiff, out);
    k_final<<<NPATH, 256, 0, stream>>>(Sm, Pm, path, Wc, bc, out);
}

// Round 8
// 91.129 us; speedup vs baseline: 1.4612x; 1.2513x over previous
//
#include <hip/hip_runtime.h>
#include <hip/hip_bf16.h>
#include <math.h>

#define NN     3072
#define NF     128
#define NHID   64
#define HEADS  8
#define LEN    8
#define NPATH  2048
#define NTK    4
#define NELEM  (NPATH*LEN)     // 16384
#define MAXDEG 128
#define SH     16              // 2 sets * 8 heads
#define KSPLIT 12
#define KCH    (NN / KSPLIT)   // 256
#define NADV   192             // nlogp tail blocks
#define NDIF   256             // diff_red tail blocks

// ================= kernel 1: GEMM (b<768) + CSR/zeroing (b>=768) =================
__global__ void k_pre(const float* __restrict__ feat,
                      const float* __restrict__ Wp, const float* __restrict__ Ws,
                      const float* __restrict__ ap, const float* __restrict__ as_,
                      const float* __restrict__ adj,
                      float* __restrict__ whg, float* __restrict__ f1g,
                      float* __restrict__ f2g, int* __restrict__ cols,
                      int* __restrict__ cnt, int* __restrict__ hist,
                      int* __restrict__ histT, float* __restrict__ out) {
    __shared__ float Fs[32][68];   // [k][r]
    __shared__ float Wsh[32][64];  // [k][c]
    int b = blockIdx.x;
    int tid = threadIdx.x;
    if (b < 768) {
        // ---- Wh = feat @ W, outputs whg[g][node][sg][64], f1g/f2g[g][node][sg]
        int rt = b % 48, sh = b / 48;
        int set = sh >> 3, head = sh & 7;
        int g = sh >> 2, sg = sh & 3;
        const float* W = (set ? Ws : Wp) + (size_t)head * NF * NHID;
        const float* a = (set ? as_ : ap) + (size_t)head * 2 * NHID;
        int tc = (tid & 15) * 4;
        int tr = (tid >> 4) * 4;
        float acc[4][4] = {};
        for (int k0 = 0; k0 < NF; k0 += 32) {
            for (int i = tid; i < 512; i += 256) {
                int r = i >> 3, kq = (i & 7) * 4;
                float4 v = *(const float4*)&feat[(size_t)(rt * 64 + r) * NF + k0 + kq];
                Fs[kq + 0][r] = v.x; Fs[kq + 1][r] = v.y;
                Fs[kq + 2][r] = v.z; Fs[kq + 3][r] = v.w;
            }
            for (int i = tid; i < 512; i += 256) {
                int k = i >> 4, cq = (i & 15) * 4;
                *(float4*)&Wsh[k][cq] = *(const float4*)&W[(size_t)(k0 + k) * NHID + cq];
            }
            __syncthreads();
            #pragma unroll
            for (int k = 0; k < 32; ++k) {
                float4 av = *(const float4*)&Fs[k][tr];
                float4 bv = *(const float4*)&Wsh[k][tc];
                float a_[4] = {av.x, av.y, av.z, av.w};
                float b_[4] = {bv.x, bv.y, bv.z, bv.w};
                #pragma unroll
                for (int i = 0; i < 4; ++i)
                    #pragma unroll
                    for (int j = 0; j < 4; ++j) acc[i][j] += a_[i] * b_[j];
            }
            __syncthreads();
        }
        #pragma unroll
        for (int i = 0; i < 4; ++i)
            *(float4*)&whg[(((size_t)g * NN + rt * 64 + tr + i) * 4 + sg) * NHID + tc] =
                *(float4*)&acc[i][0];
        float4 a1 = *(const float4*)&a[tc];
        float4 a2 = *(const float4*)&a[NHID + tc];
        float p1[4], p2[4];
        #pragma unroll
        for (int i = 0; i < 4; ++i) {
            p1[i] = acc[i][0]*a1.x + acc[i][1]*a1.y + acc[i][2]*a1.z + acc[i][3]*a1.w;
            p2[i] = acc[i][0]*a2.x + acc[i][1]*a2.y + acc[i][2]*a2.z + acc[i][3]*a2.w;
        }
        #pragma unroll
        for (int o = 1; o < 16; o <<= 1) {
            #pragma unroll
            for (int i = 0; i < 4; ++i) {
                p1[i] += __shfl_xor(p1[i], o);
                p2[i] += __shfl_xor(p2[i], o);
            }
        }
        if ((tid & 15) == 0) {
            #pragma unroll
            for (int i = 0; i < 4; ++i) {
                f1g[((size_t)g * NN + rt * 64 + tr + i) * 4 + sg] = p1[i];
                f2g[((size_t)g * NN + rt * 64 + tr + i) * 4 + sg] = p2[i];
            }
        }
        return;
    }
    // ---- CSR + zeroing
    int cb = b - 768;                      // 0..767
    if (cb < 64) {
        int i = cb * 256 + tid;            // covers 16384 >= NN + NN*NTK slots
        if (i < NN) hist[i] = 0;
        if (i < NN * NTK) histT[i] = 0;
        if (i == 0) { out[NPATH] = 0.f; out[NPATH + 1] = 0.f; }
    }
    int row  = cb * 4 + (tid >> 6);
    int lane = tid & 63;
    const float* ar = adj + (size_t)row * NN;
    int* cr = cols + (size_t)row * MAXDEG;
    int base = 0;
    for (int c0 = 0; c0 < NN; c0 += 256) {
        float4 v = *(const float4*)&ar[c0 + lane * 4];
        float e[4] = {v.x, v.y, v.z, v.w};
        #pragma unroll
        for (int q = 0; q < 4; ++q) {
            bool pred = e[q] > 0.f;
            unsigned long long bb = __ballot(pred);
            int before = __popcll(bb & ((1ull << lane) - 1ull));
            if (pred && (base + before) < MAXDEG) cr[base + before] = c0 + lane * 4 + q;
            base += __popcll(bb);
        }
    }
    if (lane == 0) cnt[row] = base < MAXDEG ? base : MAXDEG;
}

// ================= kernel 2: sparse GAT (all blocks) + path histograms (first 64) =================
__global__ void k_gat(const float* __restrict__ whg, const float* __restrict__ f1g,
                      const float* __restrict__ f2g, const int* __restrict__ cols,
                      const int* __restrict__ cnt, const int* __restrict__ path,
                      const int* __restrict__ task, int* __restrict__ hist,
                      int* __restrict__ histT, float* __restrict__ xo) {
    __shared__ float attT[4][MAXDEG][4];   // 8 KB
    __shared__ int   cls[4][MAXDEG];       // 2 KB
    int b = blockIdx.x;                    // 0..3071
    if (b < 64) {                          // fused histogram build (zeroed by k_pre)
        int i = b * 256 + threadIdx.x;     // 64*256 == NELEM
        int node = path[i];
        atomicAdd(&hist[node], 1);
        atomicAdd(&histT[node * NTK + task[i]], 1);
    }
    int g = (b & 7) >> 1;                  // sh-group -> XCD pair {2g,2g+1}
    int node4 = ((b >> 3) << 1) | (b & 1); // 0..767
    int w = threadIdx.x >> 6;
    int lane = threadIdx.x & 63;
    int node = node4 * 4 + w;
    int deg = cnt[node];
    const int* cl = cols + (size_t)node * MAXDEG;
    const float* f2p = f2g + (size_t)g * NN * 4;
    float4 f1q = *(const float4*)&f1g[((size_t)g * NN + node) * 4];
    float f1v[4] = {f1q.x, f1q.y, f1q.z, f1q.w};

    float e0[4], e1[4];
    #pragma unroll
    for (int t = 0; t < 2; ++t) {
        int l = lane + t * 64;
        bool valid = l < deg;
        int j = valid ? cl[l] : 0;
        if (valid) cls[w][l] = j;
        float4 q = *(const float4*)&f2p[(size_t)j * 4];
        float f2v[4] = {q.x, q.y, q.z, q.w};
        float* e = t ? e1 : e0;
        #pragma unroll
        for (int s = 0; s < 4; ++s) {
            float x = f1v[s] + f2v[s];
            x = (x >= 0.f) ? x : 0.2f * x;
            e[s] = valid ? x : -1e30f;
        }
    }
    float m[4], sl[4], inv[4];
    #pragma unroll
    for (int s = 0; s < 4; ++s) m[s] = fmaxf(e0[s], e1[s]);
    #pragma unroll
    for (int o = 32; o; o >>= 1)
        #pragma unroll
        for (int s = 0; s < 4; ++s) m[s] = fmaxf(m[s], __shfl_xor(m[s], o));
    float ex0[4], ex1[4];
    #pragma unroll
    for (int s = 0; s < 4; ++s) {
        ex0[s] = expf(e0[s] - m[s]);
        ex1[s] = expf(e1[s] - m[s]);
        sl[s] = ex0[s] + ex1[s];
    }
    #pragma unroll
    for (int o = 32; o; o >>= 1)
        #pragma unroll
        for (int s = 0; s < 4; ++s) sl[s] += __shfl_xor(sl[s], o);
    #pragma unroll
    for (int s = 0; s < 4; ++s) inv[s] = 1.f / sl[s];
    *(float4*)&attT[w][lane][0]      = make_float4(ex0[0], ex0[1], ex0[2], ex0[3]);
    *(float4*)&attT[w][lane + 64][0] = make_float4(ex1[0], ex1[1], ex1[2], ex1[3]);

    const float* base = whg + (size_t)g * NN * 256;
    float acc0 = 0.f, acc1 = 0.f, acc2 = 0.f, acc3 = 0.f;
    int l = 0;
    for (; l + 2 <= deg; l += 2) {
        int ja = cls[w][l], jb = cls[w][l + 1];
        const float* wa = base + (size_t)ja * 256 + lane;
        const float* wb = base + (size_t)jb * 256 + lane;
        float4 aa = *(const float4*)&attT[w][l][0];
        float4 ab = *(const float4*)&attT[w][l + 1][0];
        float va0 = wa[0], va1 = wa[64], va2 = wa[128], va3 = wa[192];
        float vb0 = wb[0], vb1 = wb[64], vb2 = wb[128], vb3 = wb[192];
        acc0 += aa.x * va0; acc1 += aa.y * va1; acc2 += aa.z * va2; acc3 += aa.w * va3;
        acc0 += ab.x * vb0; acc1 += ab.y * vb1; acc2 += ab.z * vb2; acc3 += ab.w * vb3;
    }
    if (l < deg) {
        int j = cls[w][l];
        const float* wr = base + (size_t)j * 256 + lane;
        float4 a4 = *(const float4*)&attT[w][l][0];
        acc0 += a4.x * wr[0];   acc1 += a4.y * wr[64];
        acc2 += a4.z * wr[128]; acc3 += a4.w * wr[192];
    }
    float accv[4] = {acc0, acc1, acc2, acc3};
    #pragma unroll
    for (int s = 0; s < 4; ++s) {
        float v = accv[s] * inv[s];
        v = (v > 0.f) ? v : (expf(v) - 1.f);   // ELU
        int sh = g * 4 + s;
        int set = sh >> 3, head = sh & 7;
        xo[((size_t)set * NN + node) * (HEADS * NHID) + head * NHID + lane] = v;
    }
}

// ================= kernel 3: diff partial GEMM (b<768) + nlogp/adv (b>=768) =================
__global__ void k_diffadv(const float* __restrict__ S, const float* __restrict__ P,
                          const int* __restrict__ hist, const float* __restrict__ Wsc,
                          const float* __restrict__ bsc, const int* __restrict__ histT,
                          float* __restrict__ Dp, float* __restrict__ out) {
    __shared__ float As[64][68];
    __shared__ float Bs[64][68];
    int b = blockIdx.x;
    int tid = threadIdx.x;
    if (b >= 768) {
        // ---- per-node logp + adversarial-loss partial (1 atomicAdd per block)
        int a_ = b - 768;                  // 0..191
        int wave = tid >> 6;
        int lane = tid & 63;
        float sloc = 0.f;
        #pragma unroll
        for (int i = 0; i < 4; ++i) {
            int w = a_ * 16 + wave * 4 + i;
            const float* row = S + (size_t)w * (HEADS * NHID);
            float4 v0 = *(const float4*)&row[lane * 8];
            float4 v1 = *(const float4*)&row[lane * 8 + 4];
            float vv[8] = {v0.x, v0.y, v0.z, v0.w, v1.x, v1.y, v1.z, v1.w};
            float p[4] = {0.f, 0.f, 0.f, 0.f};
            #pragma unroll
            for (int qq = 0; qq < 8; ++qq) {
                float4 wv = *(const float4*)&Wsc[(lane * 8 + qq) * 4];
                p[0] += vv[qq] * wv.x; p[1] += vv[qq] * wv.y;
                p[2] += vv[qq] * wv.z; p[3] += vv[qq] * wv.w;
            }
            for (int o = 32; o; o >>= 1) {
                p[0] += __shfl_xor(p[0], o); p[1] += __shfl_xor(p[1], o);
                p[2] += __shfl_xor(p[2], o); p[3] += __shfl_xor(p[3], o);
            }
            if (lane == 0) {
                float sg[4], mx = -1e30f;
                for (int j = 0; j < 4; ++j) {
                    sg[j] = 1.f / (1.f + expf(-(p[j] + bsc[j])));
                    mx = fmaxf(mx, sg[j]);
                }
                float ex[4], se = 0.f;
                for (int j = 0; j < 4; ++j) { ex[j] = expf(sg[j] - mx); se += ex[j]; }
                float pr[4], pe = 0.f;
                for (int j = 0; j < 4; ++j) { pr[j] = ex[j] / se; }
                for (int j = 0; j < 4; ++j) { pe += expf(pr[j]); }
                float lse = logf(pe);
                for (int j = 0; j < 4; ++j)
                    sloc += (float)histT[w * NTK + j] * (pr[j] - lse);
            }
        }
        if (lane == 0) ((float*)As)[wave] = sloc;
        __syncthreads();
        if (tid == 0) {
            float t = ((float*)As)[0] + ((float*)As)[1] + ((float*)As)[2] + ((float*)As)[3];
            if (t != 0.f) atomicAdd(&out[NPATH], -t * (1.f / (float)NELEM));
        }
        return;
    }
    // ---- diff partial: Dp[z] = S^T diag(c) P over one K-chunk
    int z = b >> 6, rem = b & 63;
    int a0 = (rem >> 3) * 64, b0 = (rem & 7) * 64;
    int kbase = z * KCH;
    int tr = (tid >> 4) * 4, tc = (tid & 15) * 4;
    float acc[4][4] = {};
    for (int k0 = 0; k0 < KCH; k0 += 64) {
        for (int i = tid; i < 64 * 16; i += 256) {
            int k = i >> 4, c4 = (i & 15) * 4;
            int krow = kbase + k0 + k;
            float wgt = (float)hist[krow];
            float4 sv = *(const float4*)&S[(size_t)krow * 512 + a0 + c4];
            As[k][c4 + 0] = sv.x * wgt; As[k][c4 + 1] = sv.y * wgt;
            As[k][c4 + 2] = sv.z * wgt; As[k][c4 + 3] = sv.w * wgt;
            float4 pv = *(const float4*)&P[(size_t)krow * 512 + b0 + c4];
            Bs[k][c4 + 0] = pv.x; Bs[k][c4 + 1] = pv.y;
            Bs[k][c4 + 2] = pv.z; Bs[k][c4 + 3] = pv.w;
        }
        __syncthreads();
        #pragma unroll
        for (int k = 0; k < 64; ++k) {
            float4 av = *(const float4*)&As[k][tr];
            float4 bv = *(const float4*)&Bs[k][tc];
            float a_[4] = {av.x, av.y, av.z, av.w};
            float b_[4] = {bv.x, bv.y, bv.z, bv.w};
            #pragma unroll
            for (int i = 0; i < 4; ++i)
                #pragma unroll
                for (int j = 0; j < 4; ++j) acc[i][j] += a_[i] * b_[j];
        }
        __syncthreads();
    }
    float* dst = Dp + (size_t)z * 512 * 512;
    #pragma unroll
    for (int i = 0; i < 4; ++i)
        *(float4*)&dst[(size_t)(a0 + tr + i) * 512 + b0 + tc] = *(float4*)&acc[i][0];
}

// ================= kernel 4: classifier (b<NPATH) + diff reduce (tail 256 blocks) =================
__global__ void k_final(const float* __restrict__ S, const float* __restrict__ P,
                        const int* __restrict__ path, const float* __restrict__ Wc,
                        const float* __restrict__ bc, const float* __restrict__ Dp,
                        float* __restrict__ out) {
    __shared__ float red[256];
    int b = blockIdx.x;
    int tid = threadIdx.x;
    if (b >= NPATH) {
        // ---- diff_loss partial: sum over (sum_z Dp[z])^2
        int e4 = (b - NPATH) * 256 + tid;   // float4 index, 65536 total
        float4 a = {0.f, 0.f, 0.f, 0.f};
        for (int z = 0; z < KSPLIT; ++z) {
            float4 v = *(const float4*)&Dp[(size_t)z * 512 * 512 + (size_t)e4 * 4];
            a.x += v.x; a.y += v.y; a.z += v.z; a.w += v.w;
        }
        red[tid] = a.x * a.x + a.y * a.y + a.z * a.z + a.w * a.w;
        __syncthreads();
        for (int o = 128; o; o >>= 1) {
            if (tid < o) red[tid] += red[tid + o];
            __syncthreads();
        }
        if (tid == 0) atomicAdd(&out[NPATH + 1], red[0]);
        return;
    }
    float s = 0.f;
    for (int m4 = tid; m4 < 2048; m4 += 256) {
        int m = m4 * 4;
        int l = m >> 10, w = m & 1023;
        int node = path[b * LEN + l];
        float4 wv = *(const float4*)&Wc[m];
        const float* src = (w < 512) ? &S[(size_t)node * 512 + w]
                                     : &P[(size_t)node * 512 + (w - 512)];
        float4 xv = *(const float4*)src;
        s += xv.x * wv.x + xv.y * wv.y + xv.z * wv.z + xv.w * wv.w;
    }
    red[tid] = s;
    __syncthreads();
    for (int o = 128; o; o >>= 1) {
        if (tid < o) red[tid] += red[tid + o];
        __syncthreads();
    }
    if (tid == 0) out[b] = 1.f / (1.f + expf(-(red[0] + bc[0])));
}

extern "C" void kernel_launch(void* const* d_in, const int* in_sizes, int n_in,
                              void* d_out, int out_size, void* d_ws, size_t ws_size,
                              hipStream_t stream) {
    const float* feat = (const float*)d_in[0];
    const float* adj  = (const float*)d_in[1];
    const int*   path = (const int*)d_in[2];
    const int*   task = (const int*)d_in[3];
    const float* Wp   = (const float*)d_in[4];
    const float* ap   = (const float*)d_in[5];
    const float* Ws   = (const float*)d_in[6];
    const float* as_  = (const float*)d_in[7];
    const float* Wsc  = (const float*)d_in[8];
    const float* bsc  = (const float*)d_in[9];
    const float* Wc   = (const float*)d_in[10];
    const float* bc   = (const float*)d_in[11];
    float* out = (float*)d_out;

    // workspace layout
    float* whg   = (float*)d_ws;                   // NN*SH*NHID ([g][node][4][64])
    float* f1g   = whg + (size_t)NN * SH * NHID;   // NN*SH ([g][node][4])
    float* f2g   = f1g + (size_t)NN * SH;
    float* xo    = f2g + (size_t)NN * SH;          // 2*3072*512
    float* Dp    = xo + (size_t)2 * NN * 512;      // KSPLIT*512*512
    int*   cols  = (int*)(Dp + (size_t)KSPLIT * 512 * 512);
    int*   cnt   = cols + (size_t)NN * MAXDEG;
    int*   hist  = cnt + NN;
    int*   histT = hist + NN;

    float* Pm = xo;                        // private (set 0)
    float* Sm = xo + (size_t)NN * 512;     // share   (set 1)

    k_pre<<<1536, 256, 0, stream>>>(feat, Wp, Ws, ap, as_, adj,
                                    whg, f1g, f2g, cols, cnt, hist, histT, out);
    k_gat<<<NN, 256, 0, stream>>>(whg, f1g, f2g, cols, cnt, path, task, hist, histT, xo);
    k_diffadv<<<768 + NADV, 256, 0, stream>>>(Sm, Pm, hist, Wsc, bsc, histT, Dp, out);
    k_final<<<NPATH + NDIF, 256, 0, stream>>>(Sm, Pm, path, Wc, bc, Dp, out);
}